// Round 1
// 616.308 us; speedup vs baseline: 1.1383x; 1.1383x over previous
//
#include <hip/hip_runtime.h>

// LSTM: T=1024 steps, B=32768 lanes, I=1, H=3.
// R2: occupancy was the wall. One-thread-per-batch = 512 waves = 0.5 waves/SIMD
// (half the SIMDs idle; OccupancyPercent 5.8, VALUBusy 38.7 ~= 77% issue on the
// occupied half -> issue-bound on half the machine). Split each batch element
// across a 4-lane quad: lane u<3 owns hidden unit u, lane 3 duplicates unit 0.
// -> 131072 threads = 2048 waves = 2 waves/SIMD on ALL 1024 SIMDs.
// h is re-shared across the quad each step with 3 quad_perm DPP broadcasts
// (VALU-latency, no LDS/bpermute). Broadcast (not rotate) keeps the per-gate
// FMA accumulation order IDENTICAL to R1 -> bitwise-identical output.

constexpr int T_STEPS = 1024;
constexpr int BATCH   = 32768;
constexpr int HID     = 3;
constexpr int NB      = 16;   // x prefetch chunk (double-buffered registers)

__device__ __forceinline__ float fsigmoid(float z) {
    float e = __builtin_amdgcn_exp2f(-1.4426950408889634f * z);
    return __builtin_amdgcn_rcpf(1.0f + e);
}
__device__ __forceinline__ float ftanh(float z) {
    float e = __builtin_amdgcn_exp2f(2.8853900817779268f * z);
    return 1.0f - 2.0f * __builtin_amdgcn_rcpf(e + 1.0f);
}

// Quad-wide broadcast of quad-lane L: CTRL = 0x00 (L=0), 0x55 (L=1), 0xAA (L=2).
template <int CTRL>
__device__ __forceinline__ float qbcast(float v) {
    return __int_as_float(
        __builtin_amdgcn_update_dpp(0, __float_as_int(v), CTRL, 0xF, 0xF, true));
}

__global__ __launch_bounds__(256, 2) void lstm_quad_kernel(
    const float* __restrict__ x,     // [T, B, 1]
    const float* __restrict__ h0,    // [B, 3]
    const float* __restrict__ c0,    // [B, 3]
    const float* __restrict__ W_ih,  // [12, 1]
    const float* __restrict__ W_hh,  // [12, 3]
    const float* __restrict__ b_ih,  // [12]
    const float* __restrict__ b_hh,  // [12]
    float* __restrict__ out)         // [T, B, 3]
{
    const int tid  = blockIdx.x * 256 + threadIdx.x;
    const int lane = tid & 3;                 // slot within quad
    const int b    = tid >> 2;                // batch element, < 32768
    const int u    = (lane == 3) ? 0 : lane;  // hidden unit this lane owns

    // Per-lane gate rows: u, 3+u, 6+u, 9+u  (PyTorch gate order i,f,g,o).
    // Weight columns kept in 0,1,2 order so FMA accumulation order matches R1.
    float wiv[4], bv[4], w0[4], w1[4], w2[4];
#pragma unroll
    for (int g = 0; g < 4; ++g) {
        const int r = 3 * g + u;
        wiv[g] = W_ih[r];
        bv[g]  = b_ih[r] + b_hh[r];
        w0[g]  = W_hh[r * HID + 0];
        w1[g]  = W_hh[r * HID + 1];
        w2[g]  = W_hh[r * HID + 2];
    }

    float h = h0[b * HID + u];
    float c = c0[b * HID + u];
    const int obase = b * HID + u;

    // Prime first x chunk (4 lanes of a quad load the same dword; TA merges).
    float cur[NB], nxt[NB];
#pragma unroll
    for (int i = 0; i < NB; ++i) cur[i] = x[i * BATCH + b];

    for (int chunk = 0; chunk < T_STEPS / NB; ++chunk) {
        // Issue next chunk's loads now; first use is NB steps away.
        const int base_next = (chunk + 1) * NB;
#pragma unroll
        for (int i = 0; i < NB; ++i) {
            int tl = base_next + i;
            if (tl >= T_STEPS) tl = T_STEPS - 1;   // harmless dup on last chunk
            nxt[i] = x[tl * BATCH + b];
        }

#pragma unroll
        for (int i = 0; i < NB; ++i) {
            const int t  = chunk * NB + i;
            const float xv = cur[i];

            // Share previous-step h across the quad (wave-lockstep => current).
            const float hv0 = qbcast<0x00>(h);
            const float hv1 = qbcast<0x55>(h);
            const float hv2 = qbcast<0xAA>(h);

            // 4 gate pre-activations for this lane's unit.
            float pi = fmaf(xv, wiv[0], bv[0]);
            float pf = fmaf(xv, wiv[1], bv[1]);
            float pg = fmaf(xv, wiv[2], bv[2]);
            float po = fmaf(xv, wiv[3], bv[3]);
            pi = fmaf(hv0, w0[0], pi); pi = fmaf(hv1, w1[0], pi); pi = fmaf(hv2, w2[0], pi);
            pf = fmaf(hv0, w0[1], pf); pf = fmaf(hv1, w1[1], pf); pf = fmaf(hv2, w2[1], pf);
            pg = fmaf(hv0, w0[2], pg); pg = fmaf(hv1, w1[2], pg); pg = fmaf(hv2, w2[2], pg);
            po = fmaf(hv0, w0[3], po); po = fmaf(hv1, w1[3], po); po = fmaf(hv2, w2[3], po);

            const float ig = fsigmoid(pi);
            const float fg = fsigmoid(pf);
            const float gg = ftanh(pg);
            const float og = fsigmoid(po);
            c = fmaf(fg, c, ig * gg);
            h = og * ftanh(c);

            // Lanes 0..2 store their unit; lane 3 (duplicate) is masked off.
            if (lane < 3) out[t * (BATCH * HID) + obase] = h;
        }

#pragma unroll
        for (int i = 0; i < NB; ++i) cur[i] = nxt[i];
    }
}

extern "C" void kernel_launch(void* const* d_in, const int* in_sizes, int n_in,
                              void* d_out, int out_size, void* d_ws, size_t ws_size,
                              hipStream_t stream) {
    const float* x    = (const float*)d_in[0];
    const float* h0   = (const float*)d_in[1];
    const float* c0   = (const float*)d_in[2];
    const float* W_ih = (const float*)d_in[3];
    const float* W_hh = (const float*)d_in[4];
    const float* b_ih = (const float*)d_in[5];
    const float* b_hh = (const float*)d_in[6];
    float* out = (float*)d_out;

    // 4 lanes per batch element: 131072 threads -> 512 blocks of 256
    // -> 2 blocks/CU -> 8 waves/CU -> 2 waves/SIMD on all 1024 SIMDs.
    dim3 grid((4 * BATCH) / 256), block(256);
    lstm_quad_kernel<<<grid, block, 0, stream>>>(x, h0, c0, W_ih, W_hh, b_ih, b_hh, out);
}

// Round 2
// 603.004 us; speedup vs baseline: 1.1635x; 1.0221x over previous
//
#include <hip/hip_runtime.h>

// LSTM: T=1024, B=32768, I=1, H=3. Quad-per-batch (R2 structure kept):
// lane u<3 owns hidden unit u, lane 3 duplicates unit 0; h shared via 3
// quad_perm DPP broadcasts. 2048 waves = 2 waves/SIMD on all 1024 SIMDs.
//
// R3: trans-issue-bound (VALUBusy 80%, ~237 issue cyc/wave/step, of which
// ~184 = 5 sigmoids/tanhs at ~16cyc per v_exp/v_rcp wave-op). Changes:
//  1. Batched reciprocal: rcp(d_i*d_f*d_g*d_o) + 9 muls replaces 4 rcps.
//  2. exp2 arg scales (-log2e / +2log2e) pre-folded into weight rows at
//     setup -> exp2(pre) directly, no per-step scale muls.
//  3. Store predicate dropped (lane 3 writes bitwise-identical value to
//     lane 0's address - benign determinate race).
//  4. Ping-pong x buffers (no cur<-nxt copy); marching output pointer.

constexpr int T_STEPS = 1024;
constexpr int BATCH   = 32768;
constexpr int HID     = 3;
constexpr int NB      = 16;   // x prefetch chunk (double-buffered registers)

constexpr float LOG2E = 1.4426950408889634f;

// Quad-wide broadcast of quad-lane L: CTRL = 0x00 (L=0), 0x55 (L=1), 0xAA (L=2).
template <int CTRL>
__device__ __forceinline__ float qbcast(float v) {
    return __int_as_float(
        __builtin_amdgcn_update_dpp(0, __float_as_int(v), CTRL, 0xF, 0xF, true));
}

__global__ __launch_bounds__(256, 2) void lstm_quad_kernel(
    const float* __restrict__ x,     // [T, B, 1]
    const float* __restrict__ h0,    // [B, 3]
    const float* __restrict__ c0,    // [B, 3]
    const float* __restrict__ W_ih,  // [12, 1]
    const float* __restrict__ W_hh,  // [12, 3]
    const float* __restrict__ b_ih,  // [12]
    const float* __restrict__ b_hh,  // [12]
    float* __restrict__ out)         // [T, B, 3]
{
    const int tid  = blockIdx.x * 256 + threadIdx.x;
    const int lane = tid & 3;                 // slot within quad
    const int b    = tid >> 2;                // batch element
    const int u    = (lane == 3) ? 0 : lane;  // hidden unit this lane owns

    // Gate rows for unit u: r = 3g+u, g in {i,f,g,o}. Scale rows so that
    // exp2(pre) gives e^{-z} (sigmoid rows) or e^{+2z} (tanh row) directly.
    float wiv[4], bv[4], w0[4], w1[4], w2[4];
#pragma unroll
    for (int g = 0; g < 4; ++g) {
        const int r = 3 * g + u;
        const float s = (g == 2) ? (2.0f * LOG2E) : (-LOG2E);
        wiv[g] = s * W_ih[r];
        bv[g]  = s * (b_ih[r] + b_hh[r]);
        w0[g]  = s * W_hh[r * HID + 0];
        w1[g]  = s * W_hh[r * HID + 1];
        w2[g]  = s * W_hh[r * HID + 2];
    }

    float h = h0[b * HID + u];
    float c = c0[b * HID + u];

    const float* xp = x + b;
    float*       op = out + b * HID + u;      // marches by B*H per step

    float bufA[NB], bufB[NB];
#pragma unroll
    for (int i = 0; i < NB; ++i) bufA[i] = xp[(size_t)i * BATCH];

    auto run_chunk = [&](int chunk, float (&cur)[NB], float (&nxt)[NB]) {
        // Issue next chunk's loads now; first use is NB steps away.
        const int base_next = (chunk + 1) * NB;
#pragma unroll
        for (int i = 0; i < NB; ++i) {
            int tl = base_next + i;
            if (tl >= T_STEPS) tl = T_STEPS - 1;   // harmless dup on last chunk
            nxt[i] = xp[(size_t)tl * BATCH];
        }

#pragma unroll
        for (int i = 0; i < NB; ++i) {
            const float xv = cur[i];

            // Share previous-step h across the quad (wave-lockstep).
            const float hv0 = qbcast<0x00>(h);
            const float hv1 = qbcast<0x55>(h);
            const float hv2 = qbcast<0xAA>(h);

            // Scaled gate pre-activations (exp2-ready).
            float pi = fmaf(xv, wiv[0], bv[0]);
            float pf = fmaf(xv, wiv[1], bv[1]);
            float pg = fmaf(xv, wiv[2], bv[2]);
            float po = fmaf(xv, wiv[3], bv[3]);
            pi = fmaf(hv0, w0[0], pi); pi = fmaf(hv1, w1[0], pi); pi = fmaf(hv2, w2[0], pi);
            pf = fmaf(hv0, w0[1], pf); pf = fmaf(hv1, w1[1], pf); pf = fmaf(hv2, w2[1], pf);
            pg = fmaf(hv0, w0[2], pg); pg = fmaf(hv1, w1[2], pg); pg = fmaf(hv2, w2[2], pg);
            po = fmaf(hv0, w0[3], po); po = fmaf(hv1, w1[3], po); po = fmaf(hv2, w2[3], po);

            // 4 exp2 (parallel), then ONE rcp for all four denominators.
            const float ei = __builtin_amdgcn_exp2f(pi);   // e^{-z_i}
            const float ef = __builtin_amdgcn_exp2f(pf);   // e^{-z_f}
            const float eg = __builtin_amdgcn_exp2f(pg);   // e^{+2 z_g}
            const float eo = __builtin_amdgcn_exp2f(po);   // e^{-z_o}
            const float di = 1.0f + ei;
            const float df = 1.0f + ef;
            const float dg = 1.0f + eg;
            const float dn = 1.0f + eo;

            const float p  = di * df;
            const float q  = dg * dn;
            const float R  = __builtin_amdgcn_rcpf(p * q);
            const float rp = q * R;                    // 1/(di*df)
            const float rq = p * R;                    // 1/(dg*dn)
            const float ig = df * rp;                  // sigmoid(z_i)
            const float fg = di * rp;                  // sigmoid(z_f)
            const float gi = dn * rq;                  // 1/dg
            const float og = dg * rq;                  // sigmoid(z_o)
            const float gg = fmaf(-2.0f, gi, 1.0f);    // tanh(z_g)

            c = fmaf(fg, c, ig * gg);
            const float ec = __builtin_amdgcn_exp2f((2.0f * LOG2E) * c);   // e^{2c}
            const float th = 1.0f - 2.0f * __builtin_amdgcn_rcpf(ec + 1.0f); // tanh(c)
            h = og * th;

            *op = h;                  // lane 3 duplicates lane 0's value: benign
            op += BATCH * HID;
        }
    };

    // Ping-pong buffers: T/NB = 64 chunks, processed in pairs.
    for (int cc = 0; cc < T_STEPS / NB; cc += 2) {
        run_chunk(cc,     bufA, bufB);
        run_chunk(cc + 1, bufB, bufA);
    }
}

extern "C" void kernel_launch(void* const* d_in, const int* in_sizes, int n_in,
                              void* d_out, int out_size, void* d_ws, size_t ws_size,
                              hipStream_t stream) {
    const float* x    = (const float*)d_in[0];
    const float* h0   = (const float*)d_in[1];
    const float* c0   = (const float*)d_in[2];
    const float* W_ih = (const float*)d_in[3];
    const float* W_hh = (const float*)d_in[4];
    const float* b_ih = (const float*)d_in[5];
    const float* b_hh = (const float*)d_in[6];
    float* out = (float*)d_out;

    // 4 lanes per batch element: 131072 threads -> 512 blocks of 256
    // -> 2 blocks/CU -> 2 waves/SIMD on all 1024 SIMDs.
    dim3 grid((4 * BATCH) / 256), block(256);
    lstm_quad_kernel<<<grid, block, 0, stream>>>(x, h0, c0, W_ih, W_hh, b_ih, b_hh, out);
}